// Round 1
// baseline (202.554 us; speedup 1.0000x reference)
//
#include <hip/hip_runtime.h>

typedef __bf16 bf16;
typedef __attribute__((ext_vector_type(8))) __bf16 bf16x8;
typedef __attribute__((ext_vector_type(4))) float f32x4;

#define LOG2E 1.44269504088896f
#define SCALE 0.125f   // 1/sqrt(64)

__device__ inline f32x4 mfma16(bf16x8 a, bf16x8 b, f32x4 c) {
    return __builtin_amdgcn_mfma_f32_16x16x32_bf16(a, b, c, 0, 0, 0);
}

// ---------------------------------------------------------------- prep ------
__global__ __launch_bounds__(256) void prep_kernel(
        const float* __restrict__ h, const float* __restrict__ x,
        const float* __restrict__ Wq, const float* __restrict__ Wk,
        const float* __restrict__ Wv, const float* __restrict__ Wo,
        const float* __restrict__ bq, const float* __restrict__ bk,
        const float* __restrict__ bv,
        bf16* __restrict__ hb, bf16* __restrict__ wpack, bf16* __restrict__ wob,
        float* __restrict__ bqkv, bf16* __restrict__ xb, float* __restrict__ sqx) {
    int stride = gridDim.x * blockDim.x;
    int tid = blockIdx.x * blockDim.x + threadIdx.x;
    for (int i = tid; i < 4096 * 512; i += stride) hb[i] = (bf16)h[i];
    for (int i = tid; i < 3 * 512 * 512; i += stride) {
        float v = (i < 262144) ? Wq[i] : (i < 524288 ? Wk[i - 262144] : Wv[i - 524288]);
        wpack[i] = (bf16)v;
    }
    for (int i = tid; i < 512 * 512; i += stride) wob[i] = (bf16)Wo[i];
    for (int i = tid; i < 1536; i += stride)
        bqkv[i] = (i < 512) ? bq[i] : (i < 1024 ? bk[i - 512] : bv[i - 1024]);
    for (int i = tid; i < 4096 * 48; i += stride) xb[i] = (bf16)x[i];
    for (int i = tid; i < 4096 * 3; i += stride) {
        int row = i / 3, c = i - row * 3;
        float s = 0.0f;
        for (int k = 0; k < 16; k++) {
            float v = (float)(bf16)x[row * 48 + c * 16 + k];
            s += v * v;
        }
        sqx[i] = s;
    }
}

// ---------------------------------------------------------- QKV GEMM --------
// out[n][m] = sum_k hb[n][k] * wpack[m][k] + bias[m], scattered to Q/K/V (B,H,N,64) bf16
__global__ __launch_bounds__(256) void gemm_qkv_kernel(
        const bf16* __restrict__ A, const bf16* __restrict__ Bm,
        const float* __restrict__ bias,
        bf16* __restrict__ Qb, bf16* __restrict__ Kb, bf16* __restrict__ Vb) {
    __shared__ bf16 Al[64][72];
    __shared__ bf16 Bl[64][72];
    int t = threadIdx.x;
    int w = t >> 6, lane = t & 63, g = lane >> 4, lo = lane & 15;
    int rowbase = blockIdx.x * 64, colbase = blockIdx.y * 64;
    int wr = (w >> 1) * 32, wc = (w & 1) * 32;
    f32x4 acc[2][2] = {};
    int sr = t >> 2, sc = (t & 3) * 16;
    for (int kb = 0; kb < 512; kb += 64) {
        *(bf16x8*)&Al[sr][sc]     = *(const bf16x8*)&A[(rowbase + sr) * 512 + kb + sc];
        *(bf16x8*)&Al[sr][sc + 8] = *(const bf16x8*)&A[(rowbase + sr) * 512 + kb + sc + 8];
        *(bf16x8*)&Bl[sr][sc]     = *(const bf16x8*)&Bm[(colbase + sr) * 512 + kb + sc];
        *(bf16x8*)&Bl[sr][sc + 8] = *(const bf16x8*)&Bm[(colbase + sr) * 512 + kb + sc + 8];
        __syncthreads();
        for (int kk = 0; kk < 64; kk += 32) {
            bf16x8 af[2], bfr[2];
            af[0]  = *(const bf16x8*)&Al[wr + lo][kk + 8 * g];
            af[1]  = *(const bf16x8*)&Al[wr + 16 + lo][kk + 8 * g];
            bfr[0] = *(const bf16x8*)&Bl[wc + lo][kk + 8 * g];
            bfr[1] = *(const bf16x8*)&Bl[wc + 16 + lo][kk + 8 * g];
            for (int ri = 0; ri < 2; ri++)
                for (int ci = 0; ci < 2; ci++)
                    acc[ri][ci] = mfma16(af[ri], bfr[ci], acc[ri][ci]);
        }
        __syncthreads();
    }
    for (int ri = 0; ri < 2; ri++)
        for (int ci = 0; ci < 2; ci++) {
            int mcol = colbase + wc + 16 * ci + lo;
            float bv = bias[mcol];
            int proj = mcol >> 9, hm = mcol & 511, head = hm >> 6, d = hm & 63;
            bf16* dst = (proj == 0) ? Qb : (proj == 1 ? Kb : Vb);
            for (int r = 0; r < 4; r++) {
                int n = rowbase + wr + 16 * ri + 4 * g + r;
                int bidx = n >> 10, i = n & 1023;
                dst[((bidx * 8 + head) * 1024 + i) * 64 + d] = (bf16)(acc[ri][ci][r] + bv);
            }
        }
}

// ----------------------------------------------------- fused attention ------
__global__ __launch_bounds__(256) void attn_kernel(
        const bf16* __restrict__ Qb, const bf16* __restrict__ Kb,
        const bf16* __restrict__ Vb, const bf16* __restrict__ xb,
        const float* __restrict__ sqx, const float* __restrict__ alpha,
        const float* __restrict__ log_sigma, bf16* __restrict__ attnout) {
    __shared__ bf16 Klds[64][72];
    __shared__ bf16 Xlds[64][56];
    __shared__ bf16 VTlds[64][72];
    __shared__ float sqj[3][64];
    __shared__ bf16 Plds[4][16][72];

    int t = threadIdx.x;
    int w = t >> 6, lane = t & 63, g = lane >> 4, lo = lane & 15;
    int b = blockIdx.z, hh = blockIdx.y;
    int i0 = blockIdx.x * 64 + w * 16;   // this wave's 16 query rows

    float alf[3], coef[3];
    for (int c = 0; c < 3; c++) {
        alf[c] = alpha[hh * 3 + c];
        float sg = expf(log_sigma[hh * 3 + c]);
        sg = fmaxf(sg, 1e-4f);
        coef[c] = -LOG2E / (2.0f * sg * sg);
    }

    // Q fragments (rows = lane&15, k-enum 8g+e, consistent with K frags)
    const bf16* Qbase = Qb + ((size_t)(b * 8 + hh) * 1024 + i0) * 64;
    bf16x8 qa[2];
    qa[0] = *(const bf16x8*)&Qbase[lo * 64 + 8 * g];
    qa[1] = *(const bf16x8*)&Qbase[lo * 64 + 32 + 8 * g];

    // Xq fragments (K padded 16->32: lanes g>=2 hold zeros)
    bf16x8 xqa[3];
    const bf16* Xibase = xb + ((size_t)(b << 10) + i0) * 48;
    for (int c = 0; c < 3; c++) {
        bf16x8 v = {};
        if (g < 2) v = *(const bf16x8*)&Xibase[lo * 48 + c * 16 + 8 * g];
        xqa[c] = v;
    }

    // per-row |x|^2 for this wave's rows (row = 4g + r)
    float sqi[3][4];
    const float* sqibase = sqx + ((size_t)(b << 10) + i0) * 3;
    for (int r = 0; r < 4; r++)
        for (int c = 0; c < 3; c++) sqi[c][r] = sqibase[(4 * g + r) * 3 + c];

    float m_r[4], l_r[4];
    f32x4 o[4];
    for (int r = 0; r < 4; r++) { m_r[r] = -1e30f; l_r[r] = 0.0f; }
    for (int td = 0; td < 4; td++) o[td] = (f32x4){0.f, 0.f, 0.f, 0.f};

    int sr = t >> 2, sc = (t & 3) * 16;
    for (int j0 = 0; j0 < 1024; j0 += 64) {
        __syncthreads();   // previous tile's reads complete before overwrite
        const bf16* Kbase = Kb + ((size_t)(b * 8 + hh) * 1024 + j0) * 64;
        *(bf16x8*)&Klds[sr][sc]     = *(const bf16x8*)&Kbase[sr * 64 + sc];
        *(bf16x8*)&Klds[sr][sc + 8] = *(const bf16x8*)&Kbase[sr * 64 + sc + 8];
        const bf16* Vbase = Vb + ((size_t)(b * 8 + hh) * 1024 + j0) * 64;
        bf16x8 v0 = *(const bf16x8*)&Vbase[sr * 64 + sc];
        bf16x8 v1 = *(const bf16x8*)&Vbase[sr * 64 + sc + 8];
        for (int q = 0; q < 8; q++) VTlds[sc + q][sr] = v0[q];
        for (int q = 0; q < 8; q++) VTlds[sc + 8 + q][sr] = v1[q];
        for (int idx = t; idx < 384; idx += 256) {
            int xr = idx / 6, xc = (idx - xr * 6) * 8;
            *(bf16x8*)&Xlds[xr][xc] = *(const bf16x8*)&xb[((size_t)(b << 10) + j0 + xr) * 48 + xc];
        }
        if (t < 192) {
            int jl = t / 3, c = t - jl * 3;
            sqj[c][jl] = sqx[((size_t)(b << 10) + j0 + jl) * 3 + c];
        }
        __syncthreads();

        // S tiles: QK^T * scale + geodesic bias
        f32x4 s[4];
        for (int tt = 0; tt < 4; tt++) {
            f32x4 acc = {};
            bf16x8 kb0 = *(const bf16x8*)&Klds[16 * tt + lo][8 * g];
            bf16x8 kb1 = *(const bf16x8*)&Klds[16 * tt + lo][32 + 8 * g];
            acc = mfma16(qa[0], kb0, acc);
            acc = mfma16(qa[1], kb1, acc);
            f32x4 ic[3];
            for (int c = 0; c < 3; c++) {
                bf16x8 xbf = {};
                if (g < 2) xbf = *(const bf16x8*)&Xlds[16 * tt + lo][c * 16 + 8 * g];
                f32x4 z = {};
                ic[c] = mfma16(xqa[c], xbf, z);
            }
            for (int r = 0; r < 4; r++) {
                float sv = acc[r] * SCALE;
                for (int c = 0; c < 3; c++) {
                    float d = sqi[c][r] + sqj[c][16 * tt + lo] - 2.0f * ic[c][r];
                    d = fmaxf(d, 0.0f);
                    sv += alf[c] * exp2f(coef[c] * d);
                }
                acc[r] = sv;
            }
            s[tt] = acc;
        }

        // online softmax (rows live on 16-lane groups: row = 4g + r)
        float pm[4], sf[4], rs[4];
        for (int r = 0; r < 4; r++)
            pm[r] = fmaxf(fmaxf(s[0][r], s[1][r]), fmaxf(s[2][r], s[3][r]));
        for (int msk = 1; msk < 16; msk <<= 1)
            for (int r = 0; r < 4; r++) pm[r] = fmaxf(pm[r], __shfl_xor(pm[r], msk));
        for (int r = 0; r < 4; r++) {
            float mn = fmaxf(m_r[r], pm[r]);
            sf[r] = exp2f((m_r[r] - mn) * LOG2E);
            m_r[r] = mn;
            rs[r] = 0.0f;
        }
        for (int tt = 0; tt < 4; tt++)
            for (int r = 0; r < 4; r++) {
                float p = exp2f((s[tt][r] - m_r[r]) * LOG2E);
                s[tt][r] = p;
                rs[r] += p;
            }
        for (int msk = 1; msk < 16; msk <<= 1)
            for (int r = 0; r < 4; r++) rs[r] += __shfl_xor(rs[r], msk);
        for (int r = 0; r < 4; r++) l_r[r] = l_r[r] * sf[r] + rs[r];

        // P -> LDS (bf16), per-wave private buffer
        for (int tt = 0; tt < 4; tt++)
            for (int r = 0; r < 4; r++)
                Plds[w][4 * g + r][16 * tt + lo] = (bf16)s[tt][r];

        for (int td = 0; td < 4; td++)
            for (int r = 0; r < 4; r++) o[td][r] *= sf[r];

        // PV: A = P (rows=lane&15), B = V^T (cols d = lane&15)
        bf16x8 pa0 = *(const bf16x8*)&Plds[w][lo][8 * g];
        bf16x8 pa1 = *(const bf16x8*)&Plds[w][lo][32 + 8 * g];
        for (int td = 0; td < 4; td++) {
            bf16x8 vb0 = *(const bf16x8*)&VTlds[16 * td + lo][8 * g];
            bf16x8 vb1 = *(const bf16x8*)&VTlds[16 * td + lo][32 + 8 * g];
            o[td] = mfma16(pa0, vb0, o[td]);
            o[td] = mfma16(pa1, vb1, o[td]);
        }
    }

    for (int td = 0; td < 4; td++)
        for (int r = 0; r < 4; r++) {
            float val = o[td][r] / l_r[r];
            int i = i0 + 4 * g + r;
            attnout[((size_t)(b << 10) + i) * 512 + hh * 64 + 16 * td + lo] = (bf16)val;
        }
}

// ----------------------------------------------------- output GEMM ----------
__global__ __launch_bounds__(256) void gemm_out_kernel(
        const bf16* __restrict__ A, const bf16* __restrict__ Bm,
        const float* __restrict__ bias, float* __restrict__ out) {
    __shared__ bf16 Al[64][72];
    __shared__ bf16 Bl[64][72];
    int t = threadIdx.x;
    int w = t >> 6, lane = t & 63, g = lane >> 4, lo = lane & 15;
    int rowbase = blockIdx.x * 64, colbase = blockIdx.y * 64;
    int wr = (w >> 1) * 32, wc = (w & 1) * 32;
    f32x4 acc[2][2] = {};
    int sr = t >> 2, sc = (t & 3) * 16;
    for (int kb = 0; kb < 512; kb += 64) {
        *(bf16x8*)&Al[sr][sc]     = *(const bf16x8*)&A[(rowbase + sr) * 512 + kb + sc];
        *(bf16x8*)&Al[sr][sc + 8] = *(const bf16x8*)&A[(rowbase + sr) * 512 + kb + sc + 8];
        *(bf16x8*)&Bl[sr][sc]     = *(const bf16x8*)&Bm[(colbase + sr) * 512 + kb + sc];
        *(bf16x8*)&Bl[sr][sc + 8] = *(const bf16x8*)&Bm[(colbase + sr) * 512 + kb + sc + 8];
        __syncthreads();
        for (int kk = 0; kk < 64; kk += 32) {
            bf16x8 af[2], bfr[2];
            af[0]  = *(const bf16x8*)&Al[wr + lo][kk + 8 * g];
            af[1]  = *(const bf16x8*)&Al[wr + 16 + lo][kk + 8 * g];
            bfr[0] = *(const bf16x8*)&Bl[wc + lo][kk + 8 * g];
            bfr[1] = *(const bf16x8*)&Bl[wc + 16 + lo][kk + 8 * g];
            for (int ri = 0; ri < 2; ri++)
                for (int ci = 0; ci < 2; ci++)
                    acc[ri][ci] = mfma16(af[ri], bfr[ci], acc[ri][ci]);
        }
        __syncthreads();
    }
    for (int ri = 0; ri < 2; ri++)
        for (int ci = 0; ci < 2; ci++) {
            int mcol = colbase + wc + 16 * ci + lo;
            float bv = bias[mcol];
            for (int r = 0; r < 4; r++) {
                int n = rowbase + wr + 16 * ri + 4 * g + r;
                out[(size_t)n * 512 + mcol] = acc[ri][ci][r] + bv;
            }
        }
}

// ---------------------------------------------------------------- launch ----
extern "C" void kernel_launch(void* const* d_in, const int* in_sizes, int n_in,
                              void* d_out, int out_size, void* d_ws, size_t ws_size,
                              hipStream_t stream) {
    const float* h  = (const float*)d_in[0];
    const float* x  = (const float*)d_in[1];
    const float* Wq = (const float*)d_in[2];
    const float* bq = (const float*)d_in[3];
    const float* Wk = (const float*)d_in[4];
    const float* bk = (const float*)d_in[5];
    const float* Wv = (const float*)d_in[6];
    const float* bv = (const float*)d_in[7];
    const float* Wo = (const float*)d_in[8];
    const float* bo = (const float*)d_in[9];
    const float* alpha     = (const float*)d_in[10];
    const float* log_sigma = (const float*)d_in[11];
    float* out = (float*)d_out;

    char* ws = (char*)d_ws;
    size_t off = 0;
    auto alloc = [&](size_t bytes) {
        char* p = ws + off;
        off += (bytes + 255) & ~(size_t)255;
        return p;
    };
    bf16*  hb      = (bf16*)alloc(4096 * 512 * 2);
    bf16*  wpack   = (bf16*)alloc(1536 * 512 * 2);
    bf16*  wob     = (bf16*)alloc(512 * 512 * 2);
    float* bqkv    = (float*)alloc(1536 * 4);
    bf16*  xb      = (bf16*)alloc(4096 * 48 * 2);
    float* sqx     = (float*)alloc(4096 * 3 * 4);
    bf16*  Qb      = (bf16*)alloc((size_t)4 * 8 * 1024 * 64 * 2);
    bf16*  Kb      = (bf16*)alloc((size_t)4 * 8 * 1024 * 64 * 2);
    bf16*  Vb      = (bf16*)alloc((size_t)4 * 8 * 1024 * 64 * 2);
    bf16*  attnout = (bf16*)alloc(4096 * 512 * 2);

    prep_kernel<<<512, 256, 0, stream>>>(h, x, Wq, Wk, Wv, Wo, bq, bk, bv,
                                         hb, wpack, wob, bqkv, xb, sqx);
    gemm_qkv_kernel<<<dim3(64, 24), 256, 0, stream>>>(hb, wpack, bqkv, Qb, Kb, Vb);
    attn_kernel<<<dim3(16, 8, 4), 256, 0, stream>>>(Qb, Kb, Vb, xb, sqx,
                                                    alpha, log_sigma, attnout);
    gemm_out_kernel<<<dim3(64, 8), 256, 0, stream>>>(attnout, wob, bo, out);
}